// Round 6
// baseline (644.924 us; speedup 1.0000x reference)
//
#include <hip/hip_runtime.h>
#include <hip/hip_fp16.h>
#include <math.h>

#define H_DIM 128
#define OUT_DIM 10
#define NBLK 32            // nodes per block in edge-parallel agg_pool

typedef __attribute__((ext_vector_type(8))) __bf16 bf16x8;
typedef __attribute__((ext_vector_type(8))) unsigned short ushort8;
typedef __attribute__((ext_vector_type(4))) float f32x4;

__device__ inline unsigned short f2bf_rne(float f) {
    unsigned int u = __float_as_uint(f);
    unsigned int r = u + 0x7FFFu + ((u >> 16) & 1u);
    return (unsigned short)(r >> 16);
}
__device__ inline float bf_lo(unsigned int u) { return __uint_as_float(u << 16); }
__device__ inline float bf_hi(unsigned int u) { return __uint_as_float(u & 0xFFFF0000u); }
__device__ inline float h2f(unsigned int e) {
    return __half2float(__ushort_as_half((unsigned short)(e & 0xFFFFu)));
}

// Accumulate one 16B fragment (8 bf16 features) scaled by n into ax/ay[4].
#define ACC4(gv, nv) do { \
    const unsigned int* _u = (const unsigned int*)&(gv); \
    ax[0] += bf_lo(_u[0]) * (nv); ay[0] += bf_hi(_u[0]) * (nv); \
    ax[1] += bf_lo(_u[1]) * (nv); ay[1] += bf_hi(_u[1]) * (nv); \
    ax[2] += bf_lo(_u[2]) * (nv); ay[2] += bf_hi(_u[2]) * (nv); \
    ax[3] += bf_lo(_u[3]) * (nv); ay[3] += bf_hi(_u[3]) * (nv); \
} while (0)

// ---------------------------------------------------------------------------
// dwordx4 gather engine, PACKED csr (4B/edge: row<<16 | fp16 norm; N<65536).
// Subgroup sub=lane>>4 handles rows 4g+sub; fl=lane&15 owns features
// fl*8..fl*8+7 (16B).  Tail pad: idx=c, norm=0.  Self-loop only in sub==0.
__device__ inline void gather_node(const int4* __restrict__ XW16,
                                   const unsigned int* __restrict__ csr,
                                   int start, int end, int c, float dc2,
                                   int sub, int fl, int lane,
                                   float ax[4], float ay[4]) {
    {   // self loop — counted once: zero scale in subgroups 1..3
        float s = (sub == 0) ? dc2 : 0.0f;
        int4 gs = XW16[(size_t)c * 16 + fl];
        const unsigned int* u = (const unsigned int*)&gs;
        ax[0] = bf_lo(u[0]) * s; ay[0] = bf_hi(u[0]) * s;
        ax[1] = bf_lo(u[1]) * s; ay[1] = bf_hi(u[1]) * s;
        ax[2] = bf_lo(u[2]) * s; ay[2] = bf_hi(u[2]) * s;
        ax[3] = bf_lo(u[3]) * s; ay[3] = bf_hi(u[3]) * s;
    }
    for (int base = start; base < end; base += 64) {
        int m = end - base; if (m > 64) m = 64;
        unsigned int ce = ((unsigned int)c) << 16;    // pad: valid idx, zero norm
        if (lane < m) ce = csr[base + lane];
        int groups = (m + 3) >> 2;
        int g = 0;
        for (; g + 3 < groups; g += 4) {              // 16 rows, 4 loads in flight
            int j = g * 4 + sub;
            unsigned int e0 = __shfl((int)ce, j);
            unsigned int e1 = __shfl((int)ce, j + 4);
            unsigned int e2 = __shfl((int)ce, j + 8);
            unsigned int e3 = __shfl((int)ce, j + 12);
            int4 g0 = XW16[(size_t)(e0 >> 16) * 16 + fl];
            int4 g1 = XW16[(size_t)(e1 >> 16) * 16 + fl];
            int4 g2 = XW16[(size_t)(e2 >> 16) * 16 + fl];
            int4 g3 = XW16[(size_t)(e3 >> 16) * 16 + fl];
            float n0 = h2f(e0), n1 = h2f(e1), n2 = h2f(e2), n3 = h2f(e3);
            ACC4(g0, n0); ACC4(g1, n1); ACC4(g2, n2); ACC4(g3, n3);
        }
        for (; g < groups; ++g) {                     // 4 rows per iteration
            int j = g * 4 + sub;
            unsigned int e = __shfl((int)ce, j);
            int4 gg = XW16[(size_t)(e >> 16) * 16 + fl];
            float n = h2f(e);
            ACC4(gg, n);
        }
    }
    #pragma unroll
    for (int q = 0; q < 4; ++q) {                     // cross-subgroup butterfly
        ax[q] += __shfl_xor(ax[q], 16); ax[q] += __shfl_xor(ax[q], 32);
        ay[q] += __shfl_xor(ay[q], 16); ay[q] += __shfl_xor(ay[q], 32);
    }
}

// ---------------------------------------------------------------------------
__global__ __launch_bounds__(256) void prep_kernel(const float* __restrict__ W1,
                                                   const float* __restrict__ W2,
                                                   unsigned short* __restrict__ Wt1Hi,
                                                   unsigned short* __restrict__ Wt1Lo,
                                                   unsigned short* __restrict__ Wt2Hi,
                                                   unsigned short* __restrict__ Wt2Lo,
                                                   int hb,
                                                   const int* __restrict__ col,
                                                   int* __restrict__ cnt,
                                                   int* __restrict__ rank, int E) {
    if (blockIdx.x < (unsigned)hb) {
        int e = blockIdx.x * 256 + threadIdx.x;
        if (e < E) rank[e] = atomicAdd(&cnt[col[e]], 1);
    } else {
        int i = (blockIdx.x - hb) * 256 + threadIdx.x;   // 0..32767
        const float* src   = (i < 16384) ? W1    : W2;
        unsigned short* dh = (i < 16384) ? Wt1Hi : Wt2Hi;
        unsigned short* dl = (i < 16384) ? Wt1Lo : Wt2Lo;
        int idx = i & 16383;
        int k = idx >> 7, n = idx & 127;
        float v = src[idx];                        // W[k][n]
        unsigned short hbv = f2bf_rne(v);
        float hf = __uint_as_float((unsigned int)hbv << 16);
        unsigned short lb = f2bf_rne(v - hf);
        dh[n * H_DIM + k] = hbv;
        dl[n * H_DIM + k] = lb;
    }
}

// ---------------------------------------------------------------------------
__global__ __launch_bounds__(256) void scan_phase1(const int* __restrict__ cnt,
                                                   int* __restrict__ blockSums,
                                                   float* __restrict__ dinv, int N) {
    __shared__ int red[256];
    int base = blockIdx.x * 1024;
    int t = threadIdx.x;
    int s = 0;
    for (int i = 0; i < 4; ++i) {
        int idx = base + t * 4 + i;
        if (idx < N) {
            int cv = cnt[idx];
            s += cv;
            dinv[idx] = rsqrtf((float)cv + 1.0f);   // deg>=1 (self loop)
        }
    }
    red[t] = s;
    __syncthreads();
    for (int d = 128; d > 0; d >>= 1) {
        if (t < d) red[t] += red[t + d];
        __syncthreads();
    }
    if (t == 0) blockSums[blockIdx.x] = red[0];
}

// ---------------------------------------------------------------------------
__global__ __launch_bounds__(256) void scan_phase23(const int* __restrict__ cnt,
                                                    const int* __restrict__ blockSums,
                                                    int* __restrict__ offs, int N, int B) {
    __shared__ int red[256];
    __shared__ int bsum[256];
    int base = blockIdx.x * 1024;
    int t = threadIdx.x;

    bsum[t] = (t < B && t < (int)blockIdx.x) ? blockSums[t] : 0;

    int v[4];
    int s = 0;
    for (int i = 0; i < 4; ++i) {
        int idx = base + t * 4 + i;
        v[i] = (idx < N) ? cnt[idx] : 0;
        s += v[i];
    }
    red[t] = s;
    __syncthreads();
    for (int d = 128; d > 0; d >>= 1) {
        if (t < d) bsum[t] += bsum[t + d];
        __syncthreads();
    }
    for (int d = 1; d < 256; d <<= 1) {
        int x = (t >= d) ? red[t - d] : 0;
        __syncthreads();
        red[t] += x;
        __syncthreads();
    }
    int run = bsum[0] + ((t == 0) ? 0 : red[t - 1]);
    for (int i = 0; i < 4; ++i) {
        int idx = base + t * 4 + i;
        if (idx < N) { offs[idx] = run; run += v[i]; }
    }
    if ((int)blockIdx.x == B - 1 && t == 255) offs[N] = run;   // == E
}

// ---------------------------------------------------------------------------
// FUSED scatter + layer-1 GEMM (f32 X read + in-register hi/lo split).
// csr entry: (row<<16) | fp16(norm).
__global__ __launch_bounds__(256) void scatter_gemm1(
        const int* __restrict__ row, const int* __restrict__ col,
        const int* __restrict__ rank, const float* __restrict__ dinv,
        const int* __restrict__ offs, unsigned int* __restrict__ csr, int E, int sb,
        const float* __restrict__ Xf,
        const unsigned short* __restrict__ WtHi, const unsigned short* __restrict__ WtLo,
        unsigned short* __restrict__ Yb, int N) {
    if (blockIdx.x < (unsigned)sb) {
        int e = blockIdx.x * 256 + threadIdx.x;
        if (e >= E) return;
        int r = row[e], c = col[e], rk = rank[e];
        int pos = offs[c] + rk;
        float norm = dinv[r] * dinv[c];
        unsigned short nb = __half_as_ushort(__float2half(norm));
        csr[pos] = (((unsigned int)r) << 16) | nb;
        return;
    }
    int blk  = blockIdx.x - sb;
    int lane = threadIdx.x & 63;
    int wv   = threadIdx.x >> 6;
    int m16  = lane & 15;
    int quad = lane >> 4;
    int nodeBase = blk * 32;

    f32x4 acc[2][2] = {};

    #pragma unroll
    for (int kt = 0; kt < 4; ++kt) {
        int k0 = kt * 32 + quad * 8;

        ushort8 aHi[2], aLo[2];
        #pragma unroll
        for (int mi = 0; mi < 2; ++mi) {
            int node = nodeBase + mi * 16 + m16;
            if (node >= N) node = N - 1;
            const float* p = Xf + (size_t)node * H_DIM + k0;
            f32x4 u = *(const f32x4*)p;
            f32x4 w = *(const f32x4*)(p + 4);
            float vv[8] = {u.x, u.y, u.z, u.w, w.x, w.y, w.z, w.w};
            #pragma unroll
            for (int j = 0; j < 8; ++j) {
                unsigned short hbv = f2bf_rne(vv[j]);
                aHi[mi][j] = hbv;
                aLo[mi][j] = f2bf_rne(vv[j] - __uint_as_float((unsigned int)hbv << 16));
            }
        }

        ushort8 bHi[2], bLo[2];
        #pragma unroll
        for (int ni = 0; ni < 2; ++ni) {
            int n = (wv * 2 + ni) * 16 + m16;
            size_t off = (size_t)n * H_DIM + k0;
            bHi[ni] = *(const ushort8*)(WtHi + off);
            bLo[ni] = *(const ushort8*)(WtLo + off);
        }

        #pragma unroll
        for (int mi = 0; mi < 2; ++mi)
            #pragma unroll
            for (int ni = 0; ni < 2; ++ni) {
                acc[mi][ni] = __builtin_amdgcn_mfma_f32_16x16x32_bf16(
                    __builtin_bit_cast(bf16x8, aHi[mi]),
                    __builtin_bit_cast(bf16x8, bHi[ni]), acc[mi][ni], 0, 0, 0);
                acc[mi][ni] = __builtin_amdgcn_mfma_f32_16x16x32_bf16(
                    __builtin_bit_cast(bf16x8, aLo[mi]),
                    __builtin_bit_cast(bf16x8, bHi[ni]), acc[mi][ni], 0, 0, 0);
                acc[mi][ni] = __builtin_amdgcn_mfma_f32_16x16x32_bf16(
                    __builtin_bit_cast(bf16x8, aHi[mi]),
                    __builtin_bit_cast(bf16x8, bLo[ni]), acc[mi][ni], 0, 0, 0);
            }
    }

    #pragma unroll
    for (int mi = 0; mi < 2; ++mi)
        #pragma unroll
        for (int r = 0; r < 4; ++r) {
            int node = nodeBase + mi * 16 + quad * 4 + r;
            if (node < N) {
                #pragma unroll
                for (int ni = 0; ni < 2; ++ni) {
                    int c = (wv * 2 + ni) * 16 + m16;
                    Yb[(size_t)node * H_DIM + c] = f2bf_rne(acc[mi][ni][r]);
                }
            }
        }
}

// ---------------------------------------------------------------------------
// FUSED layer-1 aggregation + layer-2 GEMM.  R4 structure (measured 44.7us):
// 256 thr, 4 waves x 4 nodes serial, 16-row MFMA tile.  Packed csr.
__global__ __launch_bounds__(256) void agg1_gemm2(
        const unsigned short* __restrict__ XWb,
        const float* __restrict__ dinv,
        const unsigned int* __restrict__ csr,
        const int* __restrict__ offs,
        const float* __restrict__ bias,
        const unsigned short* __restrict__ WtHi,   // W2 hi (transposed)
        const unsigned short* __restrict__ WtLo,   // W2 lo
        unsigned short* __restrict__ Yb,           // XW2 out
        int N) {
    __shared__ __align__(16) unsigned short hrow[16][136];   // +8 pad
    int lane = threadIdx.x & 63;
    int wv   = threadIdx.x >> 6;
    int sub  = lane >> 4;
    int fl   = lane & 15;
    int nodeBase = blockIdx.x * 16;
    const int4* XW16 = (const int4*)XWb;
    float4 b0 = ((const float4*)bias)[fl * 2];
    float4 b1 = ((const float4*)bias)[fl * 2 + 1];

    for (int i = 0; i < 4; ++i) {
        int c = nodeBase + wv * 4 + i;
        float ax[4] = {}, ay[4] = {};
        if (c < N) {
            int start = offs[c], end = offs[c + 1];
            float dc = dinv[c];
            gather_node(XW16, csr, start, end, c, dc * dc, sub, fl, lane, ax, ay);
            ax[0] = fmaxf(ax[0] + b0.x, 0.f); ay[0] = fmaxf(ay[0] + b0.y, 0.f);
            ax[1] = fmaxf(ax[1] + b0.z, 0.f); ay[1] = fmaxf(ay[1] + b0.w, 0.f);
            ax[2] = fmaxf(ax[2] + b1.x, 0.f); ay[2] = fmaxf(ay[2] + b1.y, 0.f);
            ax[3] = fmaxf(ax[3] + b1.z, 0.f); ay[3] = fmaxf(ay[3] + b1.w, 0.f);
        }
        if (sub == 0) {                        // 16 lanes stage the bf16 row
            unsigned int o[4];
            #pragma unroll
            for (int q = 0; q < 4; ++q)
                o[q] = (unsigned int)f2bf_rne(ax[q]) | ((unsigned int)f2bf_rne(ay[q]) << 16);
            *(int4*)&hrow[wv * 4 + i][fl * 8] = *(const int4*)o;
        }
    }
    __syncthreads();

    // ---- layer-2 GEMM: hrow[16][128] @ W2[128][128]
    int m16  = lane & 15;
    int quad = lane >> 4;
    f32x4 acc[2] = {};
    #pragma unroll
    for (int kt = 0; kt < 4; ++kt) {
        int k0 = kt * 32 + quad * 8;
        ushort8 a = *(const ushort8*)&hrow[m16][k0];
        #pragma unroll
        for (int ni = 0; ni < 2; ++ni) {
            int n = (wv * 2 + ni) * 16 + m16;
            size_t off = (size_t)n * H_DIM + k0;
            ushort8 bHi = *(const ushort8*)(WtHi + off);
            ushort8 bLo = *(const ushort8*)(WtLo + off);
            acc[ni] = __builtin_amdgcn_mfma_f32_16x16x32_bf16(
                __builtin_bit_cast(bf16x8, a),
                __builtin_bit_cast(bf16x8, bHi), acc[ni], 0, 0, 0);
            acc[ni] = __builtin_amdgcn_mfma_f32_16x16x32_bf16(
                __builtin_bit_cast(bf16x8, a),
                __builtin_bit_cast(bf16x8, bLo), acc[ni], 0, 0, 0);
        }
    }
    #pragma unroll
    for (int r = 0; r < 4; ++r) {
        int node = nodeBase + quad * 4 + r;
        if (node < N) {
            #pragma unroll
            for (int ni = 0; ni < 2; ++ni) {
                int cc = (wv * 2 + ni) * 16 + m16;
                Yb[(size_t)node * H_DIM + cc] = f2bf_rne(acc[ni][r]);
            }
        }
    }
}

// ---------------------------------------------------------------------------
// EDGE-PARALLEL layer-2 aggregation + pooling.  Block owns NBLK consecutive
// dest nodes; waves stream the block's edge range (csr sorted by dest) and
// ds_add_f32 (atomic) gathered rows into a 32x128 f32 LDS accumulator.  No
// per-node dependent chain, no butterfly.  Dest node via binary search in
// staged offs.  LDS feature layout permuted f -> (f&7)*16 + (f>>3) so one
// ds_add instruction spans 16 banks (<=4-way conflict).  Finalize: self-loop
// + bias + relu + run-accumulated pooling atomics.
__global__ __launch_bounds__(256) void agg_pool_ep(const unsigned short* __restrict__ XWb,
                                                   const float* __restrict__ dinv,
                                                   const unsigned int* __restrict__ csr,
                                                   const int* __restrict__ offs,
                                                   const float* __restrict__ bias,
                                                   const int* __restrict__ batch,
                                                   float* __restrict__ pooledSum, int N) {
    __shared__ float lacc[NBLK][132];                 // permuted feature layout
    __shared__ int   loffs[NBLK + 1];
    __shared__ int   lbatch[NBLK];
    __shared__ float ldinv[NBLK];
    int t = threadIdx.x;
    int c0 = blockIdx.x * NBLK;

    for (int i = t; i < NBLK * 132; i += 256) ((float*)lacc)[i] = 0.f;
    if (t <= NBLK) {
        int idx = c0 + t; if (idx > N) idx = N;
        loffs[t] = offs[idx];
    }
    if (t < NBLK) {
        int c = c0 + t;
        lbatch[t] = (c < N) ? batch[c] : -1;
        ldinv[t]  = (c < N) ? dinv[c] : 0.f;
    }
    __syncthreads();

    int s0 = loffs[0], s1 = loffs[NBLK];
    int lane = t & 63, wv = t >> 6, sub = lane >> 4, fl = lane & 15;
    const int4* XW16 = (const int4*)XWb;

    for (int base = s0 + wv * 64; base < s1; base += 256) {
        int m = s1 - base; if (m > 64) m = 64;
        unsigned int ce = 0;                          // pad: row 0, norm 0
        int cL = 0;
        if (lane < m) {
            ce = csr[base + lane];
            int e = base + lane;                      // binary search dest node
            int lo = 0, hi = NBLK - 1;
            #pragma unroll
            for (int it = 0; it < 5; ++it) {          // 2^5 = 32 = NBLK
                int mid = (lo + hi + 1) >> 1;
                if (loffs[mid] <= e) lo = mid; else hi = mid - 1;
            }
            cL = lo;
        }
        int groups = (m + 3) >> 2;
        int g = 0;
        #define EP_EDGE(ev, cv) do { \
            int4 gv = XW16[(size_t)((ev) >> 16) * 16 + fl]; \
            float nn = h2f(ev); \
            float* L = &lacc[cv][0]; \
            const unsigned int* u = (const unsigned int*)&gv; \
            atomicAdd(L + 0 * 16 + fl, bf_lo(u[0]) * nn); \
            atomicAdd(L + 1 * 16 + fl, bf_hi(u[0]) * nn); \
            atomicAdd(L + 2 * 16 + fl, bf_lo(u[1]) * nn); \
            atomicAdd(L + 3 * 16 + fl, bf_hi(u[1]) * nn); \
            atomicAdd(L + 4 * 16 + fl, bf_lo(u[2]) * nn); \
            atomicAdd(L + 5 * 16 + fl, bf_hi(u[2]) * nn); \
            atomicAdd(L + 6 * 16 + fl, bf_lo(u[3]) * nn); \
            atomicAdd(L + 7 * 16 + fl, bf_hi(u[3]) * nn); \
        } while (0)
        for (; g + 3 < groups; g += 4) {              // 16 edges, 4 loads in flight
            int j = g * 4 + sub;
            unsigned int e0 = __shfl((int)ce, j);      int cj0 = __shfl(cL, j);
            unsigned int e1 = __shfl((int)ce, j + 4);  int cj1 = __shfl(cL, j + 4);
            unsigned int e2 = __shfl((int)ce, j + 8);  int cj2 = __shfl(cL, j + 8);
            unsigned int e3 = __shfl((int)ce, j + 12); int cj3 = __shfl(cL, j + 12);
            int4 v0 = XW16[(size_t)(e0 >> 16) * 16 + fl];
            int4 v1 = XW16[(size_t)(e1 >> 16) * 16 + fl];
            int4 v2 = XW16[(size_t)(e2 >> 16) * 16 + fl];
            int4 v3 = XW16[(size_t)(e3 >> 16) * 16 + fl];
            float n0 = h2f(e0), n1 = h2f(e1), n2 = h2f(e2), n3 = h2f(e3);
            {
                const unsigned int* u; float* L;
                u = (const unsigned int*)&v0; L = &lacc[cj0][0];
                atomicAdd(L + 0*16 + fl, bf_lo(u[0])*n0); atomicAdd(L + 1*16 + fl, bf_hi(u[0])*n0);
                atomicAdd(L + 2*16 + fl, bf_lo(u[1])*n0); atomicAdd(L + 3*16 + fl, bf_hi(u[1])*n0);
                atomicAdd(L + 4*16 + fl, bf_lo(u[2])*n0); atomicAdd(L + 5*16 + fl, bf_hi(u[2])*n0);
                atomicAdd(L + 6*16 + fl, bf_lo(u[3])*n0); atomicAdd(L + 7*16 + fl, bf_hi(u[3])*n0);
                u = (const unsigned int*)&v1; L = &lacc[cj1][0];
                atomicAdd(L + 0*16 + fl, bf_lo(u[0])*n1); atomicAdd(L + 1*16 + fl, bf_hi(u[0])*n1);
                atomicAdd(L + 2*16 + fl, bf_lo(u[1])*n1); atomicAdd(L + 3*16 + fl, bf_hi(u[1])*n1);
                atomicAdd(L + 4*16 + fl, bf_lo(u[2])*n1); atomicAdd(L + 5*16 + fl, bf_hi(u[2])*n1);
                atomicAdd(L + 6*16 + fl, bf_lo(u[3])*n1); atomicAdd(L + 7*16 + fl, bf_hi(u[3])*n1);
                u = (const unsigned int*)&v2; L = &lacc[cj2][0];
                atomicAdd(L + 0*16 + fl, bf_lo(u[0])*n2); atomicAdd(L + 1*16 + fl, bf_hi(u[0])*n2);
                atomicAdd(L + 2*16 + fl, bf_lo(u[1])*n2); atomicAdd(L + 3*16 + fl, bf_hi(u[1])*n2);
                atomicAdd(L + 4*16 + fl, bf_lo(u[2])*n2); atomicAdd(L + 5*16 + fl, bf_hi(u[2])*n2);
                atomicAdd(L + 6*16 + fl, bf_lo(u[3])*n2); atomicAdd(L + 7*16 + fl, bf_hi(u[3])*n2);
                u = (const unsigned int*)&v3; L = &lacc[cj3][0];
                atomicAdd(L + 0*16 + fl, bf_lo(u[0])*n3); atomicAdd(L + 1*16 + fl, bf_hi(u[0])*n3);
                atomicAdd(L + 2*16 + fl, bf_lo(u[1])*n3); atomicAdd(L + 3*16 + fl, bf_hi(u[1])*n3);
                atomicAdd(L + 4*16 + fl, bf_lo(u[2])*n3); atomicAdd(L + 5*16 + fl, bf_hi(u[2])*n3);
                atomicAdd(L + 6*16 + fl, bf_lo(u[3])*n3); atomicAdd(L + 7*16 + fl, bf_hi(u[3])*n3);
            }
        }
        for (; g < groups; ++g) {
            int j = g * 4 + sub;
            unsigned int e = __shfl((int)ce, j);
            int cj = __shfl(cL, j);
            EP_EDGE(e, cj);
        }
        #undef EP_EDGE
    }
    __syncthreads();

    // ---- finalize: self-loop + bias + relu, pool over sorted batch runs
    int f = t & 127, half = t >> 7;
    float bsv = bias[f];
    int pidx = (f & 7) * 16 + (f >> 3);               // permuted LDS index
    float s = 0.f; int cur = -1;
    for (int i = 0; i < NBLK / 2; ++i) {
        int n = half * (NBLK / 2) + i;
        int c = c0 + n;
        if (c >= N) break;
        float dc = ldinv[n];
        float selfv = __uint_as_float(((unsigned int)XWb[(size_t)c * H_DIM + f]) << 16)
                      * (dc * dc);
        float val = fmaxf(lacc[n][pidx] + selfv + bsv, 0.f);
        int g = lbatch[n];
        if (g != cur) {
            if (cur >= 0) atomicAdd(&pooledSum[cur * H_DIM + f], s);
            s = 0.f; cur = g;
        }
        s += val;
    }
    if (cur >= 0) atomicAdd(&pooledSum[cur * H_DIM + f], s);
}

// ---------------------------------------------------------------------------
// Head: count via binary search on sorted batch, mean, FC, log-softmax.
__global__ __launch_bounds__(64) void head_kernel(const float* __restrict__ pooledSum,
                                                  const int* __restrict__ batch,
                                                  const float* __restrict__ Wfc,
                                                  const float* __restrict__ bfc,
                                                  float* __restrict__ out, int N) {
    __shared__ float sl[OUT_DIM + 2];
    __shared__ int bounds[2];
    int g = blockIdx.x;
    int j = threadIdx.x;
    if (j < 2) {
        int v = g + j;
        int lo = 0, hi = N;
        while (lo < hi) {
            int mid = (lo + hi) >> 1;
            if (batch[mid] < v) lo = mid + 1; else hi = mid;
        }
        bounds[j] = lo;
    }
    __syncthreads();
    int cnt = bounds[1] - bounds[0];
    float inv = 1.0f / (float)(cnt > 0 ? cnt : 1);
    if (j < OUT_DIM) {
        float acc = 0.f;
        const float* p = pooledSum + g * H_DIM;
        for (int k = 0; k < H_DIM; ++k) acc += p[k] * Wfc[k * OUT_DIM + j];
        sl[j] = acc * inv + bfc[j];
    }
    __syncthreads();
    if (j == 0) {
        float m = sl[0];
        for (int i = 1; i < OUT_DIM; ++i) m = fmaxf(m, sl[i]);
        float s = 0.f;
        for (int i = 0; i < OUT_DIM; ++i) s += expf(sl[i] - m);
        sl[OUT_DIM] = m + logf(s);
    }
    __syncthreads();
    if (j < OUT_DIM) out[g * OUT_DIM + j] = sl[j] - sl[OUT_DIM];
}

// ---------------------------------------------------------------------------
extern "C" void kernel_launch(void* const* d_in, const int* in_sizes, int n_in,
                              void* d_out, int out_size, void* d_ws, size_t ws_size,
                              hipStream_t stream) {
    const float* x     = (const float*)d_in[0];
    const int*   ei    = (const int*)  d_in[1];
    const int*   batch = (const int*)  d_in[2];
    const float* W1    = (const float*)d_in[3];
    const float* b1    = (const float*)d_in[4];
    const float* W2    = (const float*)d_in[5];
    const float* b2    = (const float*)d_in[6];
    const float* Wfc   = (const float*)d_in[7];
    const float* bfc   = (const float*)d_in[8];
    float* out = (float*)d_out;

    int N = in_sizes[2];
    int E = in_sizes[1] / 2;
    int G = out_size / OUT_DIM;
    const int* row = ei;
    const int* col = ei + E;

    // Workspace layout (ONE memset zeroes cnt+pooledSum, adjacent):
    // cnt[nAlign] | pooledSum[G*128] | offs[nAlign] | rank[E] | dinv[nAlign]
    //   | csr[E] uint (PACKED 4B/edge) | Xb[N*128] us | Hb[N*128] us
    //   | blockSums[256] | Wt{1,2}{Hi,Lo}[16384] us
    char* wsb = (char*)d_ws;
    size_t nAlign = (size_t)((N + 256) / 256) * 256;   // >= N+1
    size_t eAlign = (size_t)((E + 255) / 256) * 256;
    int*   cnt       = (int*)wsb;
    float* pooledSum = (float*)(cnt + nAlign);
    int*   offs      = (int*)(pooledSum + (size_t)G * H_DIM);
    int*   rank      = offs + nAlign;
    float* dinv      = (float*)(rank + eAlign);
    unsigned int* csr = (unsigned int*)(dinv + nAlign);
    unsigned short* Xb = (unsigned short*)(csr + eAlign);
    unsigned short* Hb = Xb + (size_t)N * H_DIM;
    int* blockSums = (int*)(Hb + (size_t)N * H_DIM);
    unsigned short* Wt1Hi = (unsigned short*)(blockSums + 256);
    unsigned short* Wt1Lo = Wt1Hi + H_DIM * H_DIM;
    unsigned short* Wt2Hi = Wt1Lo + H_DIM * H_DIM;
    unsigned short* Wt2Lo = Wt2Hi + H_DIM * H_DIM;

    int scanBlocks = (N + 1023) / 1024;   // 40 for N=40000 (<=256 supported)
    int histBlocks = (E + 255) / 256;
    int gemmBlocks = (N + 31) / 32;       // 32 nodes/block (layer 1)

    // ---- One memset for cnt + pooledSum (adjacent)
    hipMemsetAsync(cnt, 0, (nAlign + (size_t)G * H_DIM) * sizeof(int), stream);

    // ---- Fused histogram (FIRST) + W-split
    prep_kernel<<<histBlocks + 128, 256, 0, stream>>>(
        W1, W2, Wt1Hi, Wt1Lo, Wt2Hi, Wt2Lo, histBlocks, col, cnt, rank, E);

    // ---- 2-dispatch scan
    scan_phase1<<<scanBlocks, 256, 0, stream>>>(cnt, blockSums, dinv, N);
    scan_phase23<<<scanBlocks, 256, 0, stream>>>(cnt, blockSums, offs, N, scanBlocks);

    // ---- FUSED scatter + layer-1 GEMM -> Xb
    scatter_gemm1<<<histBlocks + gemmBlocks, 256, 0, stream>>>(
        row, col, rank, dinv, offs, csr, E, histBlocks,
        x, Wt1Hi, Wt1Lo, Xb, N);

    // ---- FUSED layer-1 aggregation + layer-2 GEMM -> Hb (holds XW2 now)
    int ag1Blocks = (N + 15) / 16;        // 16 nodes/block, 4 nodes/wave (R4)
    agg1_gemm2<<<ag1Blocks, 256, 0, stream>>>(Xb, dinv, csr, offs, b1,
                                              Wt2Hi, Wt2Lo, Hb, N);

    // ---- Layer-2 aggregation + pooling, EDGE-PARALLEL
    int aggBlocks = (N + NBLK - 1) / NBLK;
    agg_pool_ep<<<aggBlocks, 256, 0, stream>>>(Hb, dinv, csr, offs, b2,
                                               batch, pooledSum, N);

    // ---- Head (count/divide folded in)
    head_kernel<<<G, 64, 0, stream>>>(pooledSum, batch, Wfc, bfc, out, N);
}

// Round 7
// 224.117 us; speedup vs baseline: 2.8776x; 2.8776x over previous
//
#include <hip/hip_runtime.h>
#include <hip/hip_fp16.h>
#include <math.h>

#define H_DIM 128
#define OUT_DIM 10

typedef __attribute__((ext_vector_type(8))) __bf16 bf16x8;
typedef __attribute__((ext_vector_type(8))) unsigned short ushort8;
typedef __attribute__((ext_vector_type(4))) float f32x4;

__device__ inline unsigned short f2bf_rne(float f) {
    unsigned int u = __float_as_uint(f);
    unsigned int r = u + 0x7FFFu + ((u >> 16) & 1u);
    return (unsigned short)(r >> 16);
}
__device__ inline float bf_lo(unsigned int u) { return __uint_as_float(u << 16); }
__device__ inline float bf_hi(unsigned int u) { return __uint_as_float(u & 0xFFFF0000u); }
__device__ inline float h2f(unsigned int e) {
    return __half2float(__ushort_as_half((unsigned short)(e & 0xFFFFu)));
}

// Accumulate one 16B fragment (8 bf16 features) scaled by n into ax/ay[4].
#define ACC4(gv, nv) do { \
    const unsigned int* _u = (const unsigned int*)&(gv); \
    ax[0] += bf_lo(_u[0]) * (nv); ay[0] += bf_hi(_u[0]) * (nv); \
    ax[1] += bf_lo(_u[1]) * (nv); ay[1] += bf_hi(_u[1]) * (nv); \
    ax[2] += bf_lo(_u[2]) * (nv); ay[2] += bf_hi(_u[2]) * (nv); \
    ax[3] += bf_lo(_u[3]) * (nv); ay[3] += bf_hi(_u[3]) * (nv); \
} while (0)

// Process one staged csr segment (ce register, m valid entries).
#define SEG_BODY(ce, m) do { \
    int groups = ((m) + 3) >> 2; \
    int g = 0; \
    for (; g + 3 < groups; g += 4) { \
        int j = g * 4 + sub; \
        unsigned int e0 = __shfl((int)(ce), j); \
        unsigned int e1 = __shfl((int)(ce), j + 4); \
        unsigned int e2 = __shfl((int)(ce), j + 8); \
        unsigned int e3 = __shfl((int)(ce), j + 12); \
        int4 g0 = XW16[(size_t)(e0 >> 16) * 16 + fl]; \
        int4 g1 = XW16[(size_t)(e1 >> 16) * 16 + fl]; \
        int4 g2 = XW16[(size_t)(e2 >> 16) * 16 + fl]; \
        int4 g3 = XW16[(size_t)(e3 >> 16) * 16 + fl]; \
        float n0 = h2f(e0), n1 = h2f(e1), n2 = h2f(e2), n3 = h2f(e3); \
        ACC4(g0, n0); ACC4(g1, n1); ACC4(g2, n2); ACC4(g3, n3); \
    } \
    for (; g < groups; ++g) { \
        int j = g * 4 + sub; \
        unsigned int e = __shfl((int)(ce), j); \
        int4 gg = XW16[(size_t)(e >> 16) * 16 + fl]; \
        float n = h2f(e); \
        ACC4(gg, n); \
    } \
} while (0)

// ---------------------------------------------------------------------------
// dwordx4 gather with PRELOADED first segment + self row (hoisted by caller
// so multiple nodes' first-round-trip loads are in flight together).
// Packed csr: (row<<16)|fp16(norm), N<65536.  Self-loop only in sub==0.
__device__ inline void gather_node_pre(const int4* __restrict__ XW16,
                                       const unsigned int* __restrict__ csr,
                                       int start, int end, int c, float dc2,
                                       unsigned int ce0, int4 gs,
                                       int sub, int fl, int lane,
                                       float ax[4], float ay[4]) {
    {   // self loop — counted once: zero scale in subgroups 1..3
        float s = (sub == 0) ? dc2 : 0.0f;
        const unsigned int* u = (const unsigned int*)&gs;
        ax[0] = bf_lo(u[0]) * s; ay[0] = bf_hi(u[0]) * s;
        ax[1] = bf_lo(u[1]) * s; ay[1] = bf_hi(u[1]) * s;
        ax[2] = bf_lo(u[2]) * s; ay[2] = bf_hi(u[2]) * s;
        ax[3] = bf_lo(u[3]) * s; ay[3] = bf_hi(u[3]) * s;
    }
    int m0 = end - start; if (m0 > 64) m0 = 64;
    SEG_BODY(ce0, m0);
    for (int base = start + 64; base < end; base += 64) {   // rare: deg > 64
        int m = end - base; if (m > 64) m = 64;
        unsigned int ce = ((unsigned int)c) << 16;          // pad: zero norm
        if (lane < m) ce = csr[base + lane];
        SEG_BODY(ce, m);
    }
    #pragma unroll
    for (int q = 0; q < 4; ++q) {                     // cross-subgroup butterfly
        ax[q] += __shfl_xor(ax[q], 16); ax[q] += __shfl_xor(ax[q], 32);
        ay[q] += __shfl_xor(ay[q], 16); ay[q] += __shfl_xor(ay[q], 32);
    }
}

// Original self-fetching variant (used by agg_pool, 1 node/wave).
__device__ inline void gather_node(const int4* __restrict__ XW16,
                                   const unsigned int* __restrict__ csr,
                                   int start, int end, int c, float dc2,
                                   int sub, int fl, int lane,
                                   float ax[4], float ay[4]) {
    int m0 = end - start; if (m0 > 64) m0 = 64;
    unsigned int ce0 = ((unsigned int)c) << 16;
    if (lane < m0) ce0 = csr[start + lane];
    int4 gs = XW16[(size_t)c * 16 + fl];
    gather_node_pre(XW16, csr, start, end, c, dc2, ce0, gs, sub, fl, lane, ax, ay);
}

// ---------------------------------------------------------------------------
__global__ __launch_bounds__(256) void prep_kernel(const float* __restrict__ W1,
                                                   const float* __restrict__ W2,
                                                   unsigned short* __restrict__ Wt1Hi,
                                                   unsigned short* __restrict__ Wt1Lo,
                                                   unsigned short* __restrict__ Wt2Hi,
                                                   unsigned short* __restrict__ Wt2Lo,
                                                   int hb,
                                                   const int* __restrict__ col,
                                                   int* __restrict__ cnt,
                                                   int* __restrict__ rank, int E) {
    if (blockIdx.x < (unsigned)hb) {
        int e = blockIdx.x * 256 + threadIdx.x;
        if (e < E) rank[e] = atomicAdd(&cnt[col[e]], 1);
    } else {
        int i = (blockIdx.x - hb) * 256 + threadIdx.x;   // 0..32767
        const float* src   = (i < 16384) ? W1    : W2;
        unsigned short* dh = (i < 16384) ? Wt1Hi : Wt2Hi;
        unsigned short* dl = (i < 16384) ? Wt1Lo : Wt2Lo;
        int idx = i & 16383;
        int k = idx >> 7, n = idx & 127;
        float v = src[idx];                        // W[k][n]
        unsigned short hbv = f2bf_rne(v);
        float hf = __uint_as_float((unsigned int)hbv << 16);
        unsigned short lb = f2bf_rne(v - hf);
        dh[n * H_DIM + k] = hbv;
        dl[n * H_DIM + k] = lb;
    }
}

// ---------------------------------------------------------------------------
__global__ __launch_bounds__(256) void scan_phase1(const int* __restrict__ cnt,
                                                   int* __restrict__ blockSums,
                                                   float* __restrict__ dinv, int N) {
    __shared__ int red[256];
    int base = blockIdx.x * 1024;
    int t = threadIdx.x;
    int s = 0;
    for (int i = 0; i < 4; ++i) {
        int idx = base + t * 4 + i;
        if (idx < N) {
            int cv = cnt[idx];
            s += cv;
            dinv[idx] = rsqrtf((float)cv + 1.0f);   // deg>=1 (self loop)
        }
    }
    red[t] = s;
    __syncthreads();
    for (int d = 128; d > 0; d >>= 1) {
        if (t < d) red[t] += red[t + d];
        __syncthreads();
    }
    if (t == 0) blockSums[blockIdx.x] = red[0];
}

// ---------------------------------------------------------------------------
__global__ __launch_bounds__(256) void scan_phase23(const int* __restrict__ cnt,
                                                    const int* __restrict__ blockSums,
                                                    int* __restrict__ offs, int N, int B) {
    __shared__ int red[256];
    __shared__ int bsum[256];
    int base = blockIdx.x * 1024;
    int t = threadIdx.x;

    bsum[t] = (t < B && t < (int)blockIdx.x) ? blockSums[t] : 0;

    int v[4];
    int s = 0;
    for (int i = 0; i < 4; ++i) {
        int idx = base + t * 4 + i;
        v[i] = (idx < N) ? cnt[idx] : 0;
        s += v[i];
    }
    red[t] = s;
    __syncthreads();
    for (int d = 128; d > 0; d >>= 1) {
        if (t < d) bsum[t] += bsum[t + d];
        __syncthreads();
    }
    for (int d = 1; d < 256; d <<= 1) {
        int x = (t >= d) ? red[t - d] : 0;
        __syncthreads();
        red[t] += x;
        __syncthreads();
    }
    int run = bsum[0] + ((t == 0) ? 0 : red[t - 1]);
    for (int i = 0; i < 4; ++i) {
        int idx = base + t * 4 + i;
        if (idx < N) { offs[idx] = run; run += v[i]; }
    }
    if ((int)blockIdx.x == B - 1 && t == 255) offs[N] = run;   // == E
}

// ---------------------------------------------------------------------------
// FUSED scatter + layer-1 GEMM (f32 X read + in-register hi/lo split).
// csr entry: (row<<16) | fp16(norm).
__global__ __launch_bounds__(256) void scatter_gemm1(
        const int* __restrict__ row, const int* __restrict__ col,
        const int* __restrict__ rank, const float* __restrict__ dinv,
        const int* __restrict__ offs, unsigned int* __restrict__ csr, int E, int sb,
        const float* __restrict__ Xf,
        const unsigned short* __restrict__ WtHi, const unsigned short* __restrict__ WtLo,
        unsigned short* __restrict__ Yb, int N) {
    if (blockIdx.x < (unsigned)sb) {
        int e = blockIdx.x * 256 + threadIdx.x;
        if (e >= E) return;
        int r = row[e], c = col[e], rk = rank[e];
        int pos = offs[c] + rk;
        float norm = dinv[r] * dinv[c];
        unsigned short nb = __half_as_ushort(__float2half(norm));
        csr[pos] = (((unsigned int)r) << 16) | nb;
        return;
    }
    int blk  = blockIdx.x - sb;
    int lane = threadIdx.x & 63;
    int wv   = threadIdx.x >> 6;
    int m16  = lane & 15;
    int quad = lane >> 4;
    int nodeBase = blk * 32;

    f32x4 acc[2][2] = {};

    #pragma unroll
    for (int kt = 0; kt < 4; ++kt) {
        int k0 = kt * 32 + quad * 8;

        ushort8 aHi[2], aLo[2];
        #pragma unroll
        for (int mi = 0; mi < 2; ++mi) {
            int node = nodeBase + mi * 16 + m16;
            if (node >= N) node = N - 1;
            const float* p = Xf + (size_t)node * H_DIM + k0;
            f32x4 u = *(const f32x4*)p;
            f32x4 w = *(const f32x4*)(p + 4);
            float vv[8] = {u.x, u.y, u.z, u.w, w.x, w.y, w.z, w.w};
            #pragma unroll
            for (int j = 0; j < 8; ++j) {
                unsigned short hbv = f2bf_rne(vv[j]);
                aHi[mi][j] = hbv;
                aLo[mi][j] = f2bf_rne(vv[j] - __uint_as_float((unsigned int)hbv << 16));
            }
        }

        ushort8 bHi[2], bLo[2];
        #pragma unroll
        for (int ni = 0; ni < 2; ++ni) {
            int n = (wv * 2 + ni) * 16 + m16;
            size_t off = (size_t)n * H_DIM + k0;
            bHi[ni] = *(const ushort8*)(WtHi + off);
            bLo[ni] = *(const ushort8*)(WtLo + off);
        }

        #pragma unroll
        for (int mi = 0; mi < 2; ++mi)
            #pragma unroll
            for (int ni = 0; ni < 2; ++ni) {
                acc[mi][ni] = __builtin_amdgcn_mfma_f32_16x16x32_bf16(
                    __builtin_bit_cast(bf16x8, aHi[mi]),
                    __builtin_bit_cast(bf16x8, bHi[ni]), acc[mi][ni], 0, 0, 0);
                acc[mi][ni] = __builtin_amdgcn_mfma_f32_16x16x32_bf16(
                    __builtin_bit_cast(bf16x8, aLo[mi]),
                    __builtin_bit_cast(bf16x8, bHi[ni]), acc[mi][ni], 0, 0, 0);
                acc[mi][ni] = __builtin_amdgcn_mfma_f32_16x16x32_bf16(
                    __builtin_bit_cast(bf16x8, aHi[mi]),
                    __builtin_bit_cast(bf16x8, bLo[ni]), acc[mi][ni], 0, 0, 0);
            }
    }

    #pragma unroll
    for (int mi = 0; mi < 2; ++mi)
        #pragma unroll
        for (int r = 0; r < 4; ++r) {
            int node = nodeBase + mi * 16 + quad * 4 + r;
            if (node < N) {
                #pragma unroll
                for (int ni = 0; ni < 2; ++ni) {
                    int c = (wv * 2 + ni) * 16 + m16;
                    Yb[(size_t)node * H_DIM + c] = f2bf_rne(acc[mi][ni][r]);
                }
            }
        }
}

// ---------------------------------------------------------------------------
// FUSED layer-1 aggregation + layer-2 GEMM.  R4 structure (measured 44.7us)
// + HOISTED PROLOGUE: all 4 nodes' first csr segments + self rows issued
// together (8 loads in flight) — removes 3 of 4 serial csr round trips/wave.
__global__ __launch_bounds__(256) void agg1_gemm2(
        const unsigned short* __restrict__ XWb,
        const float* __restrict__ dinv,
        const unsigned int* __restrict__ csr,
        const int* __restrict__ offs,
        const float* __restrict__ bias,
        const unsigned short* __restrict__ WtHi,   // W2 hi (transposed)
        const unsigned short* __restrict__ WtLo,   // W2 lo
        unsigned short* __restrict__ Yb,           // XW2 out
        int N) {
    __shared__ __align__(16) unsigned short hrow[16][136];   // +8 pad
    int lane = threadIdx.x & 63;
    int wv   = threadIdx.x >> 6;
    int sub  = lane >> 4;
    int fl   = lane & 15;
    int nodeBase = blockIdx.x * 16;
    const int4* XW16 = (const int4*)XWb;
    float4 b0 = ((const float4*)bias)[fl * 2];
    float4 b1 = ((const float4*)bias)[fl * 2 + 1];

    // ---- hoisted prologue: offs, first csr segment, self row for 4 nodes
    int cN[4], st[4], en[4];
    float dc2[4];
    #pragma unroll
    for (int i = 0; i < 4; ++i) {
        int c = nodeBase + wv * 4 + i;
        bool ok = c < N;
        int cc = ok ? c : N - 1;
        cN[i] = cc;
        st[i] = ok ? offs[cc] : 0;
        en[i] = ok ? offs[cc + 1] : 0;
        float d = dinv[cc];
        dc2[i] = ok ? d * d : 0.f;
    }
    unsigned int ce0[4]; int4 gs[4];
    #pragma unroll
    for (int i = 0; i < 4; ++i) {
        int m = en[i] - st[i]; if (m > 64) m = 64;
        unsigned int pad = ((unsigned int)cN[i]) << 16;
        ce0[i] = (lane < m) ? csr[st[i] + lane] : pad;
        gs[i] = XW16[(size_t)cN[i] * 16 + fl];
    }

    #pragma unroll
    for (int i = 0; i < 4; ++i) {
        float ax[4], ay[4];
        gather_node_pre(XW16, csr, st[i], en[i], cN[i], dc2[i],
                        ce0[i], gs[i], sub, fl, lane, ax, ay);
        ax[0] = fmaxf(ax[0] + b0.x, 0.f); ay[0] = fmaxf(ay[0] + b0.y, 0.f);
        ax[1] = fmaxf(ax[1] + b0.z, 0.f); ay[1] = fmaxf(ay[1] + b0.w, 0.f);
        ax[2] = fmaxf(ax[2] + b1.x, 0.f); ay[2] = fmaxf(ay[2] + b1.y, 0.f);
        ax[3] = fmaxf(ax[3] + b1.z, 0.f); ay[3] = fmaxf(ay[3] + b1.w, 0.f);
        if (sub == 0) {                        // 16 lanes stage the bf16 row
            unsigned int o[4];
            #pragma unroll
            for (int q = 0; q < 4; ++q)
                o[q] = (unsigned int)f2bf_rne(ax[q]) | ((unsigned int)f2bf_rne(ay[q]) << 16);
            *(int4*)&hrow[wv * 4 + i][fl * 8] = *(const int4*)o;
        }
    }
    __syncthreads();

    // ---- layer-2 GEMM: hrow[16][128] @ W2[128][128]
    int m16  = lane & 15;
    int quad = lane >> 4;
    f32x4 acc[2] = {};
    #pragma unroll
    for (int kt = 0; kt < 4; ++kt) {
        int k0 = kt * 32 + quad * 8;
        ushort8 a = *(const ushort8*)&hrow[m16][k0];
        #pragma unroll
        for (int ni = 0; ni < 2; ++ni) {
            int n = (wv * 2 + ni) * 16 + m16;
            size_t off = (size_t)n * H_DIM + k0;
            ushort8 bHi = *(const ushort8*)(WtHi + off);
            ushort8 bLo = *(const ushort8*)(WtLo + off);
            acc[ni] = __builtin_amdgcn_mfma_f32_16x16x32_bf16(
                __builtin_bit_cast(bf16x8, a),
                __builtin_bit_cast(bf16x8, bHi), acc[ni], 0, 0, 0);
            acc[ni] = __builtin_amdgcn_mfma_f32_16x16x32_bf16(
                __builtin_bit_cast(bf16x8, a),
                __builtin_bit_cast(bf16x8, bLo), acc[ni], 0, 0, 0);
        }
    }
    #pragma unroll
    for (int r = 0; r < 4; ++r) {
        int node = nodeBase + quad * 4 + r;
        if (node < N) {
            #pragma unroll
            for (int ni = 0; ni < 2; ++ni) {
                int cc = (wv * 2 + ni) * 16 + m16;
                Yb[(size_t)node * H_DIM + cc] = f2bf_rne(acc[ni][r]);
            }
        }
    }
}

// ---------------------------------------------------------------------------
// Layer-2 aggregation + fused pooling.  One wave per node (R4-proven
// structure), packed csr.
__global__ __launch_bounds__(256) void agg_pool(const unsigned short* __restrict__ XWb,
                                                const float* __restrict__ dinv,
                                                const unsigned int* __restrict__ csr,
                                                const int* __restrict__ offs,
                                                const float* __restrict__ bias,
                                                const int* __restrict__ batch,
                                                float* __restrict__ pooledSum, int N) {
    int wave = (blockIdx.x * 256 + threadIdx.x) >> 6;
    int lane = threadIdx.x & 63;
    int wv   = threadIdx.x >> 6;
    int sub  = lane >> 4;
    int fl   = lane & 15;
    bool active = wave < N;

    float ax[4] = {}, ay[4] = {};
    int c = wave;
    if (active) {
        int start = offs[c], end = offs[c + 1];
        float dc = dinv[c];
        gather_node((const int4*)XWb, csr, start, end, c, dc * dc, sub, fl, lane, ax, ay);
        float4 b0 = ((const float4*)bias)[fl * 2];
        float4 b1 = ((const float4*)bias)[fl * 2 + 1];
        ax[0] = fmaxf(ax[0] + b0.x, 0.f); ay[0] = fmaxf(ay[0] + b0.y, 0.f);
        ax[1] = fmaxf(ax[1] + b0.z, 0.f); ay[1] = fmaxf(ay[1] + b0.w, 0.f);
        ax[2] = fmaxf(ax[2] + b1.x, 0.f); ay[2] = fmaxf(ay[2] + b1.y, 0.f);
        ax[3] = fmaxf(ax[3] + b1.z, 0.f); ay[3] = fmaxf(ay[3] + b1.w, 0.f);
    }

    __shared__ float lacc[4][H_DIM];
    __shared__ int lg[4];
    if (lane == 0) lg[wv] = active ? batch[c] : -1;
    if (sub == 0) {                           // 16 lanes write 8 floats each
        float4 f0; f0.x = ax[0]; f0.y = ay[0]; f0.z = ax[1]; f0.w = ay[1];
        float4 f1; f1.x = ax[2]; f1.y = ay[2]; f1.z = ax[3]; f1.w = ay[3];
        ((float4*)&lacc[wv][fl * 8])[0] = f0;
        ((float4*)&lacc[wv][fl * 8])[1] = f1;
    }
    __syncthreads();
    int t = threadIdx.x;
    if (t < H_DIM) {
        float s = 0.f; int cur = -1;
        #pragma unroll
        for (int w = 0; w < 4; ++w) {
            int g = lg[w];
            if (g < 0) continue;
            if (g != cur) {
                if (cur >= 0) atomicAdd(&pooledSum[cur * H_DIM + t], s);
                s = 0.f; cur = g;
            }
            s += lacc[w][t];
        }
        if (cur >= 0) atomicAdd(&pooledSum[cur * H_DIM + t], s);
    }
}

// ---------------------------------------------------------------------------
// Head: count via binary search on sorted batch, mean, FC, log-softmax.
__global__ __launch_bounds__(64) void head_kernel(const float* __restrict__ pooledSum,
                                                  const int* __restrict__ batch,
                                                  const float* __restrict__ Wfc,
                                                  const float* __restrict__ bfc,
                                                  float* __restrict__ out, int N) {
    __shared__ float sl[OUT_DIM + 2];
    __shared__ int bounds[2];
    int g = blockIdx.x;
    int j = threadIdx.x;
    if (j < 2) {
        int v = g + j;
        int lo = 0, hi = N;
        while (lo < hi) {
            int mid = (lo + hi) >> 1;
            if (batch[mid] < v) lo = mid + 1; else hi = mid;
        }
        bounds[j] = lo;
    }
    __syncthreads();
    int cnt = bounds[1] - bounds[0];
    float inv = 1.0f / (float)(cnt > 0 ? cnt : 1);
    if (j < OUT_DIM) {
        float acc = 0.f;
        const float* p = pooledSum + g * H_DIM;
        for (int k = 0; k < H_DIM; ++k) acc += p[k] * Wfc[k * OUT_DIM + j];
        sl[j] = acc * inv + bfc[j];
    }
    __syncthreads();
    if (j == 0) {
        float m = sl[0];
        for (int i = 1; i < OUT_DIM; ++i) m = fmaxf(m, sl[i]);
        float s = 0.f;
        for (int i = 0; i < OUT_DIM; ++i) s += expf(sl[i] - m);
        sl[OUT_DIM] = m + logf(s);
    }
    __syncthreads();
    if (j < OUT_DIM) out[g * OUT_DIM + j] = sl[j] - sl[OUT_DIM];
}

// ---------------------------------------------------------------------------
extern "C" void kernel_launch(void* const* d_in, const int* in_sizes, int n_in,
                              void* d_out, int out_size, void* d_ws, size_t ws_size,
                              hipStream_t stream) {
    const float* x     = (const float*)d_in[0];
    const int*   ei    = (const int*)  d_in[1];
    const int*   batch = (const int*)  d_in[2];
    const float* W1    = (const float*)d_in[3];
    const float* b1    = (const float*)d_in[4];
    const float* W2    = (const float*)d_in[5];
    const float* b2    = (const float*)d_in[6];
    const float* Wfc   = (const float*)d_in[7];
    const float* bfc   = (const float*)d_in[8];
    float* out = (float*)d_out;

    int N = in_sizes[2];
    int E = in_sizes[1] / 2;
    int G = out_size / OUT_DIM;
    const int* row = ei;
    const int* col = ei + E;

    // Workspace layout (ONE memset zeroes cnt+pooledSum, adjacent):
    // cnt[nAlign] | pooledSum[G*128] | offs[nAlign] | rank[E] | dinv[nAlign]
    //   | csr[E] uint (PACKED 4B/edge) | Xb[N*128] us | Hb[N*128] us
    //   | blockSums[256] | Wt{1,2}{Hi,Lo}[16384] us
    char* wsb = (char*)d_ws;
    size_t nAlign = (size_t)((N + 256) / 256) * 256;   // >= N+1
    size_t eAlign = (size_t)((E + 255) / 256) * 256;
    int*   cnt       = (int*)wsb;
    float* pooledSum = (float*)(cnt + nAlign);
    int*   offs      = (int*)(pooledSum + (size_t)G * H_DIM);
    int*   rank      = offs + nAlign;
    float* dinv      = (float*)(rank + eAlign);
    unsigned int* csr = (unsigned int*)(dinv + nAlign);
    unsigned short* Xb = (unsigned short*)(csr + eAlign);
    unsigned short* Hb = Xb + (size_t)N * H_DIM;
    int* blockSums = (int*)(Hb + (size_t)N * H_DIM);
    unsigned short* Wt1Hi = (unsigned short*)(blockSums + 256);
    unsigned short* Wt1Lo = Wt1Hi + H_DIM * H_DIM;
    unsigned short* Wt2Hi = Wt1Lo + H_DIM * H_DIM;
    unsigned short* Wt2Lo = Wt2Hi + H_DIM * H_DIM;

    int scanBlocks = (N + 1023) / 1024;   // 40 for N=40000 (<=256 supported)
    int histBlocks = (E + 255) / 256;
    int gemmBlocks = (N + 31) / 32;       // 32 nodes/block (layer 1)

    // ---- One memset for cnt + pooledSum (adjacent)
    hipMemsetAsync(cnt, 0, (nAlign + (size_t)G * H_DIM) * sizeof(int), stream);

    // ---- Fused histogram (FIRST) + W-split
    prep_kernel<<<histBlocks + 128, 256, 0, stream>>>(
        W1, W2, Wt1Hi, Wt1Lo, Wt2Hi, Wt2Lo, histBlocks, col, cnt, rank, E);

    // ---- 2-dispatch scan
    scan_phase1<<<scanBlocks, 256, 0, stream>>>(cnt, blockSums, dinv, N);
    scan_phase23<<<scanBlocks, 256, 0, stream>>>(cnt, blockSums, offs, N, scanBlocks);

    // ---- FUSED scatter + layer-1 GEMM -> Xb
    scatter_gemm1<<<histBlocks + gemmBlocks, 256, 0, stream>>>(
        row, col, rank, dinv, offs, csr, E, histBlocks,
        x, Wt1Hi, Wt1Lo, Xb, N);

    // ---- FUSED layer-1 aggregation + layer-2 GEMM -> Hb (holds XW2 now)
    int ag1Blocks = (N + 15) / 16;        // 16 nodes/block, 4 nodes/wave
    agg1_gemm2<<<ag1Blocks, 256, 0, stream>>>(Xb, dinv, csr, offs, b1,
                                              Wt2Hi, Wt2Lo, Hb, N);

    // ---- Layer-2 aggregation + fused pooling (R4-proven structure)
    int aggBlocks = (N + 3) / 4;          // 4 waves/block, 1 wave/node
    agg_pool<<<aggBlocks, 256, 0, stream>>>(Hb, dinv, csr, offs, b2,
                                            batch, pooledSum, N);

    // ---- Head (count/divide folded in)
    head_kernel<<<G, 64, 0, stream>>>(pooledSum, batch, Wfc, bfc, out, N);
}